// Round 6
// baseline (384.833 us; speedup 1.0000x reference)
//
#include <hip/hip_runtime.h>
#include <cstdint>
#include <cstddef>

// CoaT factorized attention block, MI355X/gfx950.
// R6: GEMM restructured to B-stationary barrier-free K-loop (gemm_bs):
// W-tile 64x512 (64KB) staged to LDS once (ONE barrier per block), then
// 16 K-chunks with A direct global->VGPR + LDS B-frags + MFMA, no syncs.
// Kills the per-iteration vmcnt(0)+barrier drain that pinned MfmaUtil at 21%
// across R4/R5 tile variants (m97-plateau behavior). M padded to 25600.

typedef unsigned short u16;

#define HEADS 8
#define CHD   64
#define CDIM  512
#define NTOK  785
#define BATCH 32
#define MROWS (BATCH * NTOK)   // 25120
#define MPAD  25600            // 50 * 512
#define QKVN  1536
#define IMGHW 784
#define KVSPLIT 7

typedef float  f32x4  __attribute__((ext_vector_type(4)));
typedef __bf16 bf16x8 __attribute__((ext_vector_type(8)));

__device__ __forceinline__ u16 f2bf(float f) {
  union { float f; uint32_t u; } x; x.f = f;
  uint32_t r = x.u + 0x7fffu + ((x.u >> 16) & 1u);  // RNE
  return (u16)(r >> 16);
}
__device__ __forceinline__ float bf2f(u16 u) {
  union { uint32_t u; float f; } x; x.u = ((uint32_t)u) << 16;
  return x.f;
}
// packed f32x2 -> bf16x2 (low = a, high = b)
__device__ __forceinline__ uint32_t pk2(float a, float b) {
#if __has_builtin(__builtin_amdgcn_cvt_pk_bf16_f32)
  auto v = __builtin_amdgcn_cvt_pk_bf16_f32(a, b);
  union { decltype(v) v2; uint32_t u; } cv; cv.v2 = v; return cv.u;
#else
  return (uint32_t)f2bf(a) | ((uint32_t)f2bf(b) << 16);
#endif
}

// ---------------- merged f32 -> bf16 casts (x, qkv_w, proj_w) --------------
__global__ __launch_bounds__(256)
void casts_kernel(const float* __restrict__ x, u16* __restrict__ xb,
                  const float* __restrict__ w1, u16* __restrict__ w1b,
                  const float* __restrict__ w2, u16* __restrict__ w2b) {
  const int N1 = MROWS * CDIM / 4, N2 = QKVN * CDIM / 4, N3 = CDIM * CDIM / 4;
  int i = blockIdx.x * 256 + threadIdx.x;
  const float* src; u16* dst;
  if (i < N1)           { src = x;  dst = xb;  }
  else if (i < N1 + N2) { i -= N1;  src = w1; dst = w1b; }
  else if (i < N1 + N2 + N3) { i -= N1 + N2; src = w2; dst = w2b; }
  else return;
  float4 v = reinterpret_cast<const float4*>(src)[i];
  uint2 o; o.x = pk2(v.x, v.y); o.y = pk2(v.z, v.w);
  reinterpret_cast<uint2*>(dst)[i] = o;
}

// ---------------- async global->LDS, 16B per lane --------------------------
__device__ __forceinline__ void gld_lds16(const u16* g, u16* l) {
  __builtin_amdgcn_global_load_lds((__attribute__((address_space(1))) void*)g,
                                   (__attribute__((address_space(3))) void*)l,
                                   16, 0, 0);
}

// ---------------- B-stationary bf16 MFMA GEMM, C = A @ W^T + bias ----------
// K = 512 (compile-time). Block: 512 threads = 8 waves, tile 512M x 64N.
// W-tile (64 rows x 512 k = 64KB) staged to LDS once with XOR-8 16B-chunk
// swizzle (phys chunk = logical ^ (row&7)); ONE barrier per block. K-loop:
// A-frags straight from global (per-wave rows, K-contiguous), B-frags from
// LDS (conflict-free via swizzle), 16 MFMA per 32-k chunk, no syncs ->
// compiler can keep many loads in flight across chunks.
// Grid: flat 1D, XCD-banded, N-fastest (xcd = flat&7): A M-band per XCD is
// 3.2MB -> stays hot in that XCD's 4MB L2 across its nNt tiles.
template <int OUTBF16>
__global__ __launch_bounds__(512)
void gemm_bs(const u16* __restrict__ A, const u16* __restrict__ W,
             const float* __restrict__ bias, void* __restrict__ Cout,
             int Mstore, int N, int nMt, int nNt) {
  __shared__ __align__(16) u16 lsB[64 * 512];   // 64 KB
  const int flat = blockIdx.x;
  const int xcd = flat & 7, idx = flat >> 3;
  const int nt = idx % nNt;
  const int mt = (idx / nNt) * 8 + xcd;
  if (mt >= nMt) return;
  const int tile_m = mt * 512, tile_n = nt * 64;

  const int tid  = threadIdx.x;
  const int wave = tid >> 6, lane = tid & 63;
  const int quad = lane >> 4, l16 = lane & 15;

  // stage W-tile: sweep s covers rows s*8 + wave; thread writes 16B at
  // (row, phys chunk tid&63) <- global chunk (tid&63) ^ (row&7).
#pragma unroll
  for (int s = 0; s < 8; ++s) {
    const int r = s * 8 + wave;
    const int gch = (tid & 63) ^ (r & 7);
    gld_lds16(W + (size_t)(tile_n + r) * CDIM + gch * 8, &lsB[s * 4096 + tid * 8]);
  }
  __syncthreads();   // the only barrier in this kernel

  // A base for this wave: rows tile_m + wave*64 + i*16 + l16, k = kc*32+quad*8
  const u16* abase = A + (size_t)(tile_m + wave * 64 + l16) * CDIM + quad * 8;

  f32x4 acc[4][4] = {};
#pragma unroll 4
  for (int kc = 0; kc < 16; ++kc) {
    bf16x8 af[4], bfr[4];
#pragma unroll
    for (int i = 0; i < 4; ++i)
      af[i] = *reinterpret_cast<const bf16x8*>(abase + (size_t)(i * 16) * CDIM + kc * 32);
#pragma unroll
    for (int j = 0; j < 4; ++j) {
      const int p = ((kc * 4 + quad) ^ (l16 & 7)) * 8;   // swizzled chunk
      bfr[j] = *reinterpret_cast<const bf16x8*>(&lsB[(j * 16 + l16) * CDIM + p]);
    }
#pragma unroll
    for (int i = 0; i < 4; ++i)
#pragma unroll
      for (int j = 0; j < 4; ++j)
        acc[i][j] = __builtin_amdgcn_mfma_f32_16x16x32_bf16(af[i], bfr[j], acc[i][j], 0, 0, 0);
  }

  // C/D layout: col = lane&15, row = quad*4 + reg
#pragma unroll
  for (int i = 0; i < 4; ++i) {
    const int mbase = tile_m + wave * 64 + i * 16 + quad * 4;
#pragma unroll
    for (int j = 0; j < 4; ++j) {
      const int n  = tile_n + j * 16 + l16;
      const float bv = bias[n];
      const float v0 = acc[i][j][0] + bv, v1 = acc[i][j][1] + bv;
      const float v2 = acc[i][j][2] + bv, v3 = acc[i][j][3] + bv;
      if (OUTBF16) {
        u16* cp = reinterpret_cast<u16*>(Cout) + (size_t)mbase * N + n;
        const uint32_t p01 = pk2(v0, v1), p23 = pk2(v2, v3);
        if (mbase + 0 < Mstore) cp[0]            = (u16)p01;
        if (mbase + 1 < Mstore) cp[(size_t)N]    = (u16)(p01 >> 16);
        if (mbase + 2 < Mstore) cp[(size_t)N*2]  = (u16)p23;
        if (mbase + 3 < Mstore) cp[(size_t)N*3]  = (u16)(p23 >> 16);
      } else {
        float* cp = reinterpret_cast<float*>(Cout) + (size_t)mbase * N + n;
        if (mbase + 0 < Mstore) cp[0]           = v0;
        if (mbase + 1 < Mstore) cp[(size_t)N]   = v1;
        if (mbase + 2 < Mstore) cp[(size_t)N*2] = v2;
        if (mbase + 3 < Mstore) cp[(size_t)N*3] = v3;
      }
    }
  }
}

// ---------------- kv partials + exp-sum partials ---------------------------
// kvpart[bh][split][c][d] = sum_{n in split} exp(k[n,c]) * v[n,d]
// kvsum [bh][split][c]    = sum_{n in split} exp(k[n,c])
__global__ __launch_bounds__(256)
void kv_kernel(const u16* __restrict__ qkv, float* __restrict__ kvpart,
               float* __restrict__ kvsum) {
  const int bh = blockIdx.x, split = blockIdx.y;
  const int b = bh >> 3, h = bh & 7;
  const int n_start = split * 113;
  const int n_end = min(NTOK, n_start + 113);
  const int t = threadIdx.x;
  const int d = t & 63, cq = t >> 6;
  __shared__ float e_s[32 * 64];
  __shared__ float v_s[32 * 64];
  const u16* kbase = qkv + (size_t)(b * NTOK) * QKVN + CDIM + h * CHD;
  const u16* vbase = kbase + CDIM;
  float acc[16];
#pragma unroll
  for (int i = 0; i < 16; ++i) acc[i] = 0.f;
  float s_part = 0.f;

  for (int n0 = n_start; n0 < n_end; n0 += 32) {
    const int nc = min(32, n_end - n0);
    __syncthreads();
    for (int i = t; i < nc * 64; i += 256) {
      const int nl = i >> 6, c = i & 63;
      const float e = __expf(bf2f(kbase[(size_t)(n0 + nl) * QKVN + c]));
      e_s[i] = e; s_part += e;
      v_s[i] = bf2f(vbase[(size_t)(n0 + nl) * QKVN + c]);
    }
    __syncthreads();
    for (int nl = 0; nl < nc; ++nl) {
      const float vv = v_s[nl * 64 + d];
#pragma unroll
      for (int i = 0; i < 16; ++i)
        acc[i] += e_s[nl * 64 + cq * 16 + i] * vv;
    }
  }
#pragma unroll
  for (int i = 0; i < 16; ++i) {
    const int c = cq * 16 + i;
    kvpart[(((size_t)bh * KVSPLIT + split) * 64 + c) * 64 + d] = acc[i];
  }
  __syncthreads();
  e_s[t] = s_part;
  __syncthreads();
  if (t < 64)
    kvsum[((size_t)bh * KVSPLIT + split) * 64 + t] =
        e_s[t] + e_s[64 + t] + e_s[128 + t] + e_s[192 + t];
}

// ---------------- reduce partials -> kvT[bh][d][c] bf16 (B-operand layout) -
__global__ __launch_bounds__(256)
void kv_reduce_kernel(const float* __restrict__ kvpart, const float* __restrict__ kvsum,
                      u16* __restrict__ kvT) {
  const int bh = blockIdx.x;
  const int t = threadIdx.x;
  const int d = t & 63, cq = t >> 6;
#pragma unroll
  for (int cc = 0; cc < 16; ++cc) {
    const int c = cq * 16 + cc;
    float s = 0.f, S = 0.f;
#pragma unroll
    for (int sp = 0; sp < KVSPLIT; ++sp) {
      s += kvpart[(((size_t)bh * KVSPLIT + sp) * 64 + c) * 64 + d];
      S += kvsum[((size_t)bh * KVSPLIT + sp) * 64 + c];
    }
    kvT[(size_t)bh * 4096 + d * 64 + c] = f2bf(s / S);
  }
}

// ---------------- depthwise conv + EV fuse ---------------------------------
template <int KS>
__device__ __forceinline__ void conv_head(
    const u16* __restrict__ qkv, const float* __restrict__ wgt,
    const float* __restrict__ bias, int b, int head, int hh, int yt,
    u16* __restrict__ evbuf, u16* __restrict__ ls) {
  constexpr int PAD = KS / 2;
  constexpr int RIN = 4 + 2 * PAD;
  const int t = threadIdx.x;
  const int y0 = yt * 4;
  const u16* vimg = qkv + (size_t)(b * NTOK + 1) * QKVN + 2 * CDIM + head * 64;
  const int c8 = (t & 7) * 8;
  for (int pi = t >> 3; pi < RIN * 28; pi += 32) {
    const int ry = pi / 28, rx = pi - ry * 28;
    const int yy = y0 - PAD + ry;
    uint4 val = {0, 0, 0, 0};
    if (yy >= 0 && yy < 28)
      val = *reinterpret_cast<const uint4*>(vimg + (size_t)(yy * 28 + rx) * QKVN + c8);
    *reinterpret_cast<uint4*>(ls + pi * 64 + c8) = val;
  }
  __syncthreads();
  const int d = t & 63, yl = t >> 6;
  float wr[KS * KS];
  const float* wp = wgt + (hh * 64 + d) * KS * KS;
#pragma unroll
  for (int i = 0; i < KS * KS; ++i) wr[i] = wp[i];
  const float bv = bias[hh * 64 + d];
  float acc[28];
#pragma unroll
  for (int x = 0; x < 28; ++x) acc[x] = bv;
#pragma unroll
  for (int xx = 0; xx < 28; ++xx) {
    float col[KS];
#pragma unroll
    for (int r = 0; r < KS; ++r)
      col[r] = bf2f(ls[((yl + r) * 28 + xx) * 64 + d]);
#pragma unroll
    for (int j = 0; j < KS; ++j) {
      const int x = xx + PAD - j;
      if (x >= 0 && x < 28) {
#pragma unroll
        for (int r = 0; r < KS; ++r)
          acc[x] += col[r] * wr[r * KS + j];
      }
    }
  }
  const int p0 = (y0 + yl) * 28;
  const u16* qrow = qkv + (size_t)(b * NTOK + 1 + p0) * QKVN + head * 64 + d;
  u16* obase = evbuf + (((size_t)(b * 8 + head)) * IMGHW + p0) * 64 + d;
#pragma unroll
  for (int x = 0; x < 28; ++x) {
    const float ev = acc[x] * bf2f(qrow[(size_t)x * QKVN]);
    obase[(size_t)x * 64] = f2bf(ev);
  }
}

__global__ __launch_bounds__(256)
void conv_all_kernel(const u16* __restrict__ qkv,
                     const float* __restrict__ w3, const float* __restrict__ b3,
                     const float* __restrict__ w5, const float* __restrict__ b5,
                     const float* __restrict__ w7, const float* __restrict__ b7,
                     u16* __restrict__ evbuf) {
  __shared__ __align__(16) u16 ls[10 * 28 * 64];
  const int b = blockIdx.x, h = blockIdx.y, yt = blockIdx.z;
  if (h < 2)      conv_head<3>(qkv, w3, b3, b, h, h,     yt, evbuf, ls);
  else if (h < 5) conv_head<5>(qkv, w5, b5, b, h, h - 2, yt, evbuf, ls);
  else            conv_head<7>(qkv, w7, b7, b, h, h - 5, yt, evbuf, ls);
}

// ---------------- combine: factor_att via MFMA + CRPE ----------------------
__global__ __launch_bounds__(256)
void combine_kernel(const u16* __restrict__ qkv, const u16* __restrict__ kvT,
                    const u16* __restrict__ evbuf, u16* __restrict__ attn) {
  const int bh = blockIdx.x;
  const int b = bh >> 3, h = bh & 7;
  const int wave = threadIdx.x >> 6, lane = threadIdx.x & 63;
  const int quad = lane >> 4, l16 = lane & 15;
  const int tokbase = blockIdx.y * 256 + wave * 64;

  const u16* kvb = kvT + (size_t)bh * 4096;
  bf16x8 bfr[4][2];
#pragma unroll
  for (int j = 0; j < 4; ++j)
#pragma unroll
    for (int kk = 0; kk < 2; ++kk)
      bfr[j][kk] = *reinterpret_cast<const bf16x8*>(
          &kvb[(j * 16 + l16) * 64 + kk * 32 + quad * 8]);

  bf16x8 af[4][2];
#pragma unroll
  for (int i = 0; i < 4; ++i) {
    const int tok = min(tokbase + i * 16 + l16, NTOK - 1);
    const u16* qrow = qkv + (size_t)(b * NTOK + tok) * QKVN + h * CHD;
    af[i][0] = *reinterpret_cast<const bf16x8*>(&qrow[quad * 8]);
    af[i][1] = *reinterpret_cast<const bf16x8*>(&qrow[32 + quad * 8]);
  }

  f32x4 acc[4][4] = {};
#pragma unroll
  for (int kk = 0; kk < 2; ++kk)
#pragma unroll
    for (int i = 0; i < 4; ++i)
#pragma unroll
      for (int j = 0; j < 4; ++j)
        acc[i][j] = __builtin_amdgcn_mfma_f32_16x16x32_bf16(af[i][kk], bfr[j][kk], acc[i][j], 0, 0, 0);

  const float scale = 0.125f;
  const u16* evb = evbuf + (size_t)bh * IMGHW * 64;
#pragma unroll
  for (int i = 0; i < 4; ++i) {
#pragma unroll
    for (int r = 0; r < 4; ++r) {
      const int tok = tokbase + i * 16 + quad * 4 + r;
      if (tok < NTOK) {
#pragma unroll
        for (int j = 0; j < 4; ++j) {
          const int d = j * 16 + l16;
          float out = scale * acc[i][j][r];
          if (tok > 0) out += bf2f(evb[(size_t)(tok - 1) * 64 + d]);
          attn[(size_t)(b * NTOK + tok) * CDIM + h * CHD + d] = f2bf(out);
        }
      }
    }
  }
}

// ---------------- launch ---------------------------------------------------
extern "C" void kernel_launch(void* const* d_in, const int* in_sizes, int n_in,
                              void* d_out, int out_size, void* d_ws, size_t ws_size,
                              hipStream_t stream) {
  const float* x      = (const float*)d_in[0];
  const float* qkv_w  = (const float*)d_in[1];
  const float* qkv_b  = (const float*)d_in[2];
  const float* proj_w = (const float*)d_in[3];
  const float* proj_b = (const float*)d_in[4];
  const float* w3 = (const float*)d_in[5];
  const float* b3 = (const float*)d_in[6];
  const float* w5 = (const float*)d_in[7];
  const float* b5 = (const float*)d_in[8];
  const float* w7 = (const float*)d_in[9];
  const float* b7 = (const float*)d_in[10];
  float* out = (float*)d_out;

  char* p = (char*)d_ws;
  u16* xb    = (u16*)p;   p += (size_t)MPAD * CDIM * 2;      // 26.2 MB
  u16* wqb   = (u16*)p;   p += (size_t)QKVN * CDIM * 2;
  u16* wpb   = (u16*)p;   p += (size_t)CDIM * CDIM * 2;
  u16* qkvb  = (u16*)p;   p += (size_t)MPAD * QKVN * 2;      // 78.6 MB
  float* kvsum = (float*)p; p += (size_t)256 * KVSPLIT * 64 * 4;
  u16* kvT   = (u16*)p;   p += (size_t)256 * 64 * 64 * 2;
  // kvpart (f32, 29.4 MB) and evbuf (bf16, 25.7 MB) share one region.
  char* shared_region = p;
  float* kvpart = (float*)shared_region;
  u16*   evbuf  = (u16*)shared_region;
  p += (size_t)256 * KVSPLIT * 64 * 64 * 4;
  u16* attn  = (u16*)p;   p += (size_t)MPAD * CDIM * 2;      // 26.2 MB

  // 1. casts (single launch)
  {
    const int total = MROWS * CDIM / 4 + QKVN * CDIM / 4 + CDIM * CDIM / 4;
    casts_kernel<<<(total + 255) / 256, 256, 0, stream>>>(x, xb, qkv_w, wqb, proj_w, wpb);
  }
  // 2. qkv = x @ qkv_w^T + qkv_b (bf16 out). nMt=50, nNt=24. 8*ceil(50/8)*24.
  gemm_bs<1><<<8 * 7 * 24, 512, 0, stream>>>(xb, wqb, qkv_b, qkvb,
                                             MPAD, QKVN, 50, 24);
  // 3. kv partials + exp-sums
  kv_kernel<<<dim3(256, KVSPLIT), 256, 0, stream>>>(qkvb, kvpart, kvsum);
  kv_reduce_kernel<<<256, 256, 0, stream>>>(kvpart, kvsum, kvT);
  // 4. depthwise convs + EV fuse
  conv_all_kernel<<<dim3(BATCH, HEADS, 7), 256, 0, stream>>>(
      qkvb, w3, b3, w5, b5, w7, b7, evbuf);
  // 5. factor_att + CRPE -> attn (bf16)
  combine_kernel<<<dim3(256, 4), 256, 0, stream>>>(qkvb, kvT, evbuf, attn);
  // 6. out = attn @ proj_w^T + proj_b (f32 out). nMt=50, nNt=8.
  gemm_bs<0><<<8 * 7 * 8, 512, 0, stream>>>(attn, wpb, proj_b, out,
                                            MROWS, CDIM, 50, 8);
}